// Round 7
// baseline (463.140 us; speedup 1.0000x reference)
//
#include <hip/hip_runtime.h>

// HierarchicalSoftmax: out[b, c*320 + t] = (x_b · topW[:,c] + top_b[c]) + (x_b · botW[t,:] + bot_b[t])
// B=1024, NHID=128, NCLASSES=320, PER_CLASS=320, row = 102400 fp32, out = 419.4 MB.
//
// Ledger: dur_us = ~272 us re-poison fill (6.2 TB/s, FETCH~8KB) + kernel time.
//   R0 fused+nt: 447.2 | R1 fused plain: 441.7 | R4 defused plain: 458.2
//   => kernel ~170-186 us (~2.45 TB/s) across THREE structures: loads/barriers/fusion exonerated.
// Theory: L2 write-allocate (RFO) on store miss doubles HBM traffic (read 400MiB + write 400MiB
//   ~ 135 us @6.2) — fill avoids it (FETCH~8KB, likely nt/no-allocate stores).
// Single-variable A/B vs R4 (458.2): K2 stores -> __builtin_nontemporal_store.
//   Predict: RFO true -> dur ~375-395. Unchanged -> nt exonerated; next = graph-overhead probe.
// (R6: third resubmission — acquisition timeouts; never measured.)

#define BATCH      1024
#define NHID       128
#define NCLASSES   320
#define PER_CLASS  320
#define ROW_ELEMS  (NCLASSES * PER_CLASS)    // 102400
#define ROW_F4     (ROW_ELEMS / 4)           // 25600
#define PC_F4      (PER_CLASS / 4)           // 80
#define LPR        (NCLASSES + PER_CLASS)    // 640 logits per row
#define LPR_F4     (LPR / 4)                 // 160
#define WS_BYTES   ((size_t)BATCH * LPR * sizeof(float))  // 2.62 MB

#define STHREADS   256
#define SGRID      2048
#define TOTAL_F4   (BATCH * ROW_F4)          // 26,214,400
#define SSTRIDE    (SGRID * STHREADS)        // 524,288
#define SITERS     (TOTAL_F4 / SSTRIDE)      // 50 exactly -> no tail, no bounds check

typedef float f32x4 __attribute__((ext_vector_type(4)));

// ---------------- K1: logits -> ws[b*640 + {c | 320+t}] ----------------
__global__ __launch_bounds__(LPR) void hs_logits_kernel(
    const float* __restrict__ inputs,     // [B, NHID]
    const float* __restrict__ top_W,      // [NHID, NCLASSES] (k-major)
    const float* __restrict__ top_b,      // [NCLASSES]
    const float* __restrict__ bottom_W,   // [PER_CLASS, NHID]
    const float* __restrict__ bottom_b,   // [PER_CLASS]
    float* __restrict__ ws)               // [B, 640]
{
    __shared__ __align__(16) float s_in[NHID];
    const int b   = blockIdx.x;
    const int tid = threadIdx.x;          // 0..639, exactly one dot each

    if (tid < NHID) s_in[tid] = inputs[b * NHID + tid];
    __syncthreads();

    float acc;
    if (tid < NCLASSES) {
        acc = top_b[tid];
        #pragma unroll 8
        for (int k = 0; k < NHID; ++k)
            acc += s_in[k] * top_W[k * NCLASSES + tid];      // coalesced across tid
    } else {
        const int t = tid - NCLASSES;
        acc = bottom_b[t];
        const f32x4* w4 = (const f32x4*)(bottom_W + t * NHID);
        #pragma unroll 8
        for (int k4 = 0; k4 < NHID / 4; ++k4) {
            f32x4 w = w4[k4];
            acc += s_in[4*k4+0]*w.x + s_in[4*k4+1]*w.y
                 + s_in[4*k4+2]*w.z + s_in[4*k4+3]*w.w;
        }
    }
    ws[b * LPR + tid] = acc;
}

// ---------------- K2: pure stream, memset-shaped, NT stores ----------------
// out4[g] = ws_top[g/25600][ (g%25600)/80 ] + ws_bot4[g/25600][ (g%25600)%80 ]
__global__ __launch_bounds__(STHREADS, 8) void hs_stream_kernel(
    const float* __restrict__ ws,         // [B, 640]; 2.62 MB -> L2-resident
    float* __restrict__ out)
{
    const f32x4* __restrict__ ws4  = (const f32x4*)ws;
    f32x4* __restrict__ out4 = (f32x4*)out;

    unsigned g = blockIdx.x * STHREADS + threadIdx.x;
    #pragma unroll 5
    for (int it = 0; it < SITERS; ++it, g += SSTRIDE) {
        const unsigned b  = g / ROW_F4;          // magic mul
        const unsigned r  = g - b * ROW_F4;
        const unsigned c  = r / PC_F4;           // magic mul
        const unsigned t4 = r - c * PC_F4;
        const float tv = ws[b * LPR + c];                      // 1-2 lines/wave, L2 hit
        const f32x4 bv = ws4[b * LPR_F4 + (NCLASSES/4) + t4];  // coalesced 16B/lane, L2 hit
        f32x4 v;
        v.x = tv + bv.x;
        v.y = tv + bv.y;
        v.z = tv + bv.z;
        v.w = tv + bv.w;
        __builtin_nontemporal_store(v, &out4[g]);              // nt: L2 no-allocate (RFO test)
    }
}

// ---------------- fallback (R1 fused kernel) if ws unavailable ----------------
#define HALVES      2
#define CLS_PER_BLK (NCLASSES / HALVES)
#define FTHREADS    320
#define C_PER_ITER  (FTHREADS / PC_F4)
#define NITER       (CLS_PER_BLK / C_PER_ITER)

__global__ __launch_bounds__(FTHREADS) void hs_fused_kernel(
    const float* __restrict__ inputs, const float* __restrict__ top_W,
    const float* __restrict__ top_b, const float* __restrict__ bottom_W,
    const float* __restrict__ bottom_b, float* __restrict__ out)
{
    __shared__ __align__(16) float s_in[NHID];
    __shared__ float s_top[CLS_PER_BLK];
    __shared__ __align__(16) float s_bot[PER_CLASS];
    const int b = blockIdx.x, h = blockIdx.y, tid = threadIdx.x;
    if (tid < NHID) s_in[tid] = inputs[b * NHID + tid];
    __syncthreads();
    for (int j = tid; j < CLS_PER_BLK + PER_CLASS; j += FTHREADS) {
        float acc;
        if (j < CLS_PER_BLK) {
            const int c = h * CLS_PER_BLK + j;
            acc = top_b[c];
            #pragma unroll 8
            for (int k = 0; k < NHID; ++k) acc += s_in[k] * top_W[k * NCLASSES + c];
            s_top[j] = acc;
        } else {
            const int t = j - CLS_PER_BLK;
            acc = bottom_b[t];
            const f32x4* w4 = (const f32x4*)(bottom_W + t * NHID);
            #pragma unroll 8
            for (int k4 = 0; k4 < NHID / 4; ++k4) {
                f32x4 w = w4[k4];
                acc += s_in[4*k4+0]*w.x + s_in[4*k4+1]*w.y + s_in[4*k4+2]*w.z + s_in[4*k4+3]*w.w;
            }
            s_bot[t] = acc;
        }
    }
    __syncthreads();
    const int c_off = tid / PC_F4;
    const int t4    = tid - c_off * PC_F4;
    const f32x4 bv  = ((const f32x4*)s_bot)[t4];
    f32x4* outp = (f32x4*)out + (size_t)b * ROW_F4 + h * (CLS_PER_BLK * PC_F4) + c_off * PC_F4 + t4;
    #pragma unroll 8
    for (int it = 0; it < NITER; ++it) {
        const float tv = s_top[it * C_PER_ITER + c_off];
        f32x4 v;
        v.x = tv + bv.x; v.y = tv + bv.y; v.z = tv + bv.z; v.w = tv + bv.w;
        outp[it * (C_PER_ITER * PC_F4)] = v;
    }
}

extern "C" void kernel_launch(void* const* d_in, const int* in_sizes, int n_in,
                              void* d_out, int out_size, void* d_ws, size_t ws_size,
                              hipStream_t stream) {
    const float* inputs   = (const float*)d_in[0];
    const float* top_W    = (const float*)d_in[1];
    const float* top_b    = (const float*)d_in[2];
    const float* bottom_W = (const float*)d_in[3];
    const float* bottom_b = (const float*)d_in[4];
    float* out = (float*)d_out;

    if (d_ws != nullptr && ws_size >= WS_BYTES) {
        float* ws = (float*)d_ws;
        hs_logits_kernel<<<BATCH, LPR, 0, stream>>>(inputs, top_W, top_b, bottom_W, bottom_b, ws);
        hs_stream_kernel<<<SGRID, STHREADS, 0, stream>>>(ws, out);
    } else {
        hs_fused_kernel<<<dim3(BATCH, HALVES), FTHREADS, 0, stream>>>(
            inputs, top_W, top_b, bottom_W, bottom_b, out);
    }
}

// Round 8
// 450.038 us; speedup vs baseline: 1.0291x; 1.0291x over previous
//
#include <hip/hip_runtime.h>

// HierarchicalSoftmax: out[b, c*320 + t] = (x_b · topW[:,c] + top_b[c]) + (x_b · botW[t,:] + bot_b[t])
// B=1024, NHID=128, NCLASSES=320, PER_CLASS=320, row = 102400 fp32, out = 419.4 MB.
//
// Ledger: dur_us = ~268 us re-poison fill (6.25 TB/s, FETCH~8KB, 10% occ) + kernel time.
//   R0 fused+nt 447 | R1 fused plain 442 | R4 defused plain 458 | R7 defused nt 463
//   => kernel ~170-195 us (~2.4 TB/s) across FOUR variants.
// Exonerated: fusion/barriers, nt-vs-plain (R7 null), RFO (fill uses plain stores, FETCH~8KB),
//   per-block contiguity (R1 tie), occupancy-too-low, VALU issue rate.
// Live theory: WRITE-STREAM COUNT. Fill = ~819 waves, long sequential cursors -> ~3 streams/HBM
//   channel -> 6.2 TB/s. Ours = 8192 waves / interleaved 1KB cursors -> ~32/channel -> row thrash.
// R8: K2 = fill-mimic: 256 blocks x 256thr (1024 waves), ONE WAVE = ONE ROW = 409.6KB sequential
//   stream; logits in LDS (lgkmcnt, decoupled from store vmcnt); store is the only VMEM op.
//   Predict: right -> dur ~350-370. Wrong (~455) -> R9 double-write diagnostic for counters.

#define BATCH      1024
#define NHID       128
#define NCLASSES   320
#define PER_CLASS  320
#define ROW_ELEMS  (NCLASSES * PER_CLASS)    // 102400
#define ROW_F4     (ROW_ELEMS / 4)           // 25600
#define PC_F4      (PER_CLASS / 4)           // 80
#define LPR        (NCLASSES + PER_CLASS)    // 640 logits per row
#define LPR_F4     (LPR / 4)                 // 160
#define WS_BYTES   ((size_t)BATCH * LPR * sizeof(float))  // 2.62 MB

#define K2_BLOCKS  256
#define K2_THREADS 256
#define RPB        (BATCH / K2_BLOCKS)       // 4 rows per block == waves per block
#define ITERS_PW   (ROW_F4 / 64)             // 400 f32x4 stores per wave (per row)

typedef float f32x4 __attribute__((ext_vector_type(4)));

// ---------------- K1: logits -> ws[b*640 + {c | 320+t}] ----------------
__global__ __launch_bounds__(LPR) void hs_logits_kernel(
    const float* __restrict__ inputs,     // [B, NHID]
    const float* __restrict__ top_W,      // [NHID, NCLASSES] (k-major)
    const float* __restrict__ top_b,      // [NCLASSES]
    const float* __restrict__ bottom_W,   // [PER_CLASS, NHID]
    const float* __restrict__ bottom_b,   // [PER_CLASS]
    float* __restrict__ ws)               // [B, 640]
{
    __shared__ __align__(16) float s_in[NHID];
    const int b   = blockIdx.x;
    const int tid = threadIdx.x;          // 0..639, exactly one dot each

    if (tid < NHID) s_in[tid] = inputs[b * NHID + tid];
    __syncthreads();

    float acc;
    if (tid < NCLASSES) {
        acc = top_b[tid];
        #pragma unroll 8
        for (int k = 0; k < NHID; ++k)
            acc += s_in[k] * top_W[k * NCLASSES + tid];      // coalesced across tid
    } else {
        const int t = tid - NCLASSES;
        acc = bottom_b[t];
        const f32x4* w4 = (const f32x4*)(bottom_W + t * NHID);
        #pragma unroll 8
        for (int k4 = 0; k4 < NHID / 4; ++k4) {
            f32x4 w = w4[k4];
            acc += s_in[4*k4+0]*w.x + s_in[4*k4+1]*w.y
                 + s_in[4*k4+2]*w.z + s_in[4*k4+3]*w.w;
        }
    }
    ws[b * LPR + tid] = acc;
}

// ---------------- K2: fill-mimic stream. 1 wave = 1 row, sequential 409.6KB ----------------
__global__ __launch_bounds__(K2_THREADS) void hs_stream_kernel(
    const float* __restrict__ ws,         // [B, 640]
    float* __restrict__ out)
{
    __shared__ __align__(16) float s_log[RPB][LPR];   // 4 x 640 x 4B = 10.24 KB

    const int b   = blockIdx.x;
    const int tid = threadIdx.x;

    // Stage this block's 4 rows of logits (2560 floats) into LDS, vectorized.
    const f32x4* wsrc = (const f32x4*)(ws + (size_t)b * RPB * LPR);
    f32x4* sdst = (f32x4*)&s_log[0][0];
    for (int j = tid; j < RPB * LPR_F4; j += K2_THREADS)
        sdst[j] = wsrc[j];
    __syncthreads();

    const int w    = tid >> 6;            // wave id 0..3 -> row
    const int lane = tid & 63;
    const float* srow  = s_log[w];                       // 640 logits for this row
    const f32x4* srow4 = (const f32x4*)(srow + NCLASSES);// bottom 320 as 80 f32x4
    f32x4* outp = (f32x4*)out + (size_t)(b * RPB + w) * ROW_F4;

    // Inner loop: 2 LDS reads (lgkmcnt) + ~6 VALU + 1 global_store_dwordx4 (vmcnt).
    // Store is the ONLY vmem op -> fire-and-forget; unroll 8 -> 8 stores in flight/wave.
    #pragma unroll 8
    for (int it = 0; it < ITERS_PW; ++it) {
        const unsigned g  = lane + it * 64;      // 0..25599, wave-sequential
        const unsigned c  = g / PC_F4;           // magic mul
        const unsigned t4 = g - c * PC_F4;
        const float tv = srow[c];                // ds_read_b32, 1-2 distinct addrs/wave
        const f32x4 bv = srow4[t4];              // ds_read_b128, contiguous, conflict-free
        f32x4 v;
        v.x = tv + bv.x;
        v.y = tv + bv.y;
        v.z = tv + bv.z;
        v.w = tv + bv.w;
        outp[g] = v;                             // 1KB/wave/iter, pure sequential cursor
    }
}

// ---------------- fallback (R1 fused kernel) if ws unavailable ----------------
#define HALVES      2
#define CLS_PER_BLK (NCLASSES / HALVES)
#define FTHREADS    320
#define C_PER_ITER  (FTHREADS / PC_F4)
#define NITER       (CLS_PER_BLK / C_PER_ITER)

__global__ __launch_bounds__(FTHREADS) void hs_fused_kernel(
    const float* __restrict__ inputs, const float* __restrict__ top_W,
    const float* __restrict__ top_b, const float* __restrict__ bottom_W,
    const float* __restrict__ bottom_b, float* __restrict__ out)
{
    __shared__ __align__(16) float s_in[NHID];
    __shared__ float s_top[CLS_PER_BLK];
    __shared__ __align__(16) float s_bot[PER_CLASS];
    const int b = blockIdx.x, h = blockIdx.y, tid = threadIdx.x;
    if (tid < NHID) s_in[tid] = inputs[b * NHID + tid];
    __syncthreads();
    for (int j = tid; j < CLS_PER_BLK + PER_CLASS; j += FTHREADS) {
        float acc;
        if (j < CLS_PER_BLK) {
            const int c = h * CLS_PER_BLK + j;
            acc = top_b[c];
            #pragma unroll 8
            for (int k = 0; k < NHID; ++k) acc += s_in[k] * top_W[k * NCLASSES + c];
            s_top[j] = acc;
        } else {
            const int t = j - CLS_PER_BLK;
            acc = bottom_b[t];
            const f32x4* w4 = (const f32x4*)(bottom_W + t * NHID);
            #pragma unroll 8
            for (int k4 = 0; k4 < NHID / 4; ++k4) {
                f32x4 w = w4[k4];
                acc += s_in[4*k4+0]*w.x + s_in[4*k4+1]*w.y + s_in[4*k4+2]*w.z + s_in[4*k4+3]*w.w;
            }
            s_bot[t] = acc;
        }
    }
    __syncthreads();
    const int c_off = tid / PC_F4;
    const int t4    = tid - c_off * PC_F4;
    const f32x4 bv  = ((const f32x4*)s_bot)[t4];
    f32x4* outp = (f32x4*)out + (size_t)b * ROW_F4 + h * (CLS_PER_BLK * PC_F4) + c_off * PC_F4 + t4;
    #pragma unroll 8
    for (int it = 0; it < NITER; ++it) {
        const float tv = s_top[it * C_PER_ITER + c_off];
        f32x4 v;
        v.x = tv + bv.x; v.y = tv + bv.y; v.z = tv + bv.z; v.w = tv + bv.w;
        outp[it * (C_PER_ITER * PC_F4)] = v;
    }
}

extern "C" void kernel_launch(void* const* d_in, const int* in_sizes, int n_in,
                              void* d_out, int out_size, void* d_ws, size_t ws_size,
                              hipStream_t stream) {
    const float* inputs   = (const float*)d_in[0];
    const float* top_W    = (const float*)d_in[1];
    const float* top_b    = (const float*)d_in[2];
    const float* bottom_W = (const float*)d_in[3];
    const float* bottom_b = (const float*)d_in[4];
    float* out = (float*)d_out;

    if (d_ws != nullptr && ws_size >= WS_BYTES) {
        float* ws = (float*)d_ws;
        hs_logits_kernel<<<BATCH, LPR, 0, stream>>>(inputs, top_W, top_b, bottom_W, bottom_b, ws);
        hs_stream_kernel<<<K2_BLOCKS, K2_THREADS, 0, stream>>>(ws, out);
    } else {
        hs_fused_kernel<<<dim3(BATCH, HALVES), FTHREADS, 0, stream>>>(
            inputs, top_W, top_b, bottom_W, bottom_b, out);
    }
}